// Round 1
// baseline (60815.448 us; speedup 1.0000x reference)
//
#include <hip/hip_runtime.h>
#include <math.h>

namespace {
constexpr int Bn = 128, Ln = 256, En = 512, Hn = 512;

// ws layout (float offsets)
constexpr long WS_CTX  = 1024;                       // [B][L][H] = ctx[b,l,o]
constexpr long WS_H    = WS_CTX + (long)Bn * Ln * Hn;
constexpr long WS_C    = WS_H   + (long)Bn * Hn;
constexpr long WS_HL   = WS_C   + (long)Bn * Hn;
constexpr long WS_INP  = WS_HL  + (long)Bn * Hn;
constexpr long WS_HS   = WS_INP + (long)Bn * Hn;
constexpr long WS_DEC  = WS_HS  + (long)Bn * Hn;
constexpr long WS_ATT  = WS_DEC + (long)Bn * En;
constexpr long WS_MASK = WS_ATT + (long)Bn * Ln;

// out layout (float offsets)
constexpr long OUT_PTR = (long)Bn * Ln * Ln;   // 8388608
constexpr long OUT_HF  = OUT_PTR + (long)Bn * Ln;
constexpr long OUT_CF  = OUT_HF + (long)Bn * Hn;
}

struct PParams {
  const float *emb, *dec0, *h0, *c0;
  const float *Wih, *bih, *Whh, *bhh;
  const float *Who, *bho, *Wa_in, *ba_in, *V;
  float *ws, *out;
};

// ---------------- device-scope grid barrier (all blocks co-resident) --------
__device__ __forceinline__ void gsync(unsigned* bar, unsigned* gen, unsigned target, int nblk) {
  __syncthreads();
  if (threadIdx.x == 0) {
    __threadfence();  // make prior writes device-visible
    unsigned n = __hip_atomic_fetch_add(bar, 1u, __ATOMIC_ACQ_REL, __HIP_MEMORY_SCOPE_AGENT);
    if (n == (unsigned)(nblk - 1)) {
      __hip_atomic_store(bar, 0u, __ATOMIC_RELAXED, __HIP_MEMORY_SCOPE_AGENT);
      __hip_atomic_store(gen, target, __ATOMIC_RELEASE, __HIP_MEMORY_SCOPE_AGENT);
    } else {
      while (__hip_atomic_load(gen, __ATOMIC_ACQUIRE, __HIP_MEMORY_SCOPE_AGENT) < target) {
        __builtin_amdgcn_s_sleep(2);
      }
    }
    __threadfence();  // acquire: invalidate stale caches before reading others' data
  }
  __syncthreads();
}

// stage one [32 rows x 256 k] fp32 tile into LDS as swizzled float4 (Xs[32][64])
__device__ __forceinline__ void stage_tile(float4* __restrict__ Xs, const float* __restrict__ src,
                                           int bt, int koff, int tid) {
  const int r  = tid >> 4;    // 0..31 (row within b-tile)
  const int ks = tid & 15;    // 16 threads per row
  const float4* g = (const float4*)(src + (size_t)(bt * 32 + r) * 512 + koff);
#pragma unroll
  for (int u = 0; u < 4; ++u) {
    int k4 = ks * 4 + u;
    Xs[r * 64 + (k4 ^ (r & 7))] = g[k4];   // XOR swizzle kills b128 bank aliasing
  }
}

__device__ __forceinline__ float xread(const float4* Xs, int bi, int k4, float4* out) {
  *out = Xs[bi * 64 + (k4 ^ (bi & 7))];
  return 0.f;
}

// ---------------- ctx precompute: ctx[b,l,o] = context[b,l,:]·Wa_ctx[o,:] + ba_ctx[o]
__launch_bounds__(256)
__global__ void ctx_precompute(const float* __restrict__ context,
                               const float* __restrict__ Wa,
                               const float* __restrict__ ba,
                               float* __restrict__ ws) {
  __shared__ __align__(16) float As[16 * 68];
  __shared__ __align__(16) float Wsm[16 * 68];
  float* ctx = ws + WS_CTX;
  const int mt = blockIdx.x >> 3;   // 512 tiles of 64 rows (b,l)
  const int nt = blockIdx.x & 7;    // 8 tiles of 64 cols (o)
  const int t = threadIdx.x;
  const int tm = t & 15, tn = t >> 4;
  float acc00=0,acc01=0,acc02=0,acc03=0, acc10=0,acc11=0,acc12=0,acc13=0;
  float acc20=0,acc21=0,acc22=0,acc23=0, acc30=0,acc31=0,acc32=0,acc33=0;

  for (int kt = 0; kt < 32; ++kt) {
    __syncthreads();
    {
      const int m = t >> 2, k4 = t & 3;
      float4 a = *(const float4*)(context + (size_t)(mt * 64 + m) * 512 + kt * 16 + k4 * 4);
      As[(k4*4+0)*68 + m] = a.x; As[(k4*4+1)*68 + m] = a.y;
      As[(k4*4+2)*68 + m] = a.z; As[(k4*4+3)*68 + m] = a.w;
      float4 w = *(const float4*)(Wa + (size_t)(nt * 64 + m) * 512 + kt * 16 + k4 * 4);
      Wsm[(k4*4+0)*68 + m] = w.x; Wsm[(k4*4+1)*68 + m] = w.y;
      Wsm[(k4*4+2)*68 + m] = w.z; Wsm[(k4*4+3)*68 + m] = w.w;
    }
    __syncthreads();
#pragma unroll
    for (int k = 0; k < 16; ++k) {
      float4 a4 = *(const float4*)(As + k * 68 + tm * 4);
      float4 b4 = *(const float4*)(Wsm + k * 68 + tn * 4);
      acc00 = fmaf(a4.x, b4.x, acc00); acc01 = fmaf(a4.x, b4.y, acc01);
      acc02 = fmaf(a4.x, b4.z, acc02); acc03 = fmaf(a4.x, b4.w, acc03);
      acc10 = fmaf(a4.y, b4.x, acc10); acc11 = fmaf(a4.y, b4.y, acc11);
      acc12 = fmaf(a4.y, b4.z, acc12); acc13 = fmaf(a4.y, b4.w, acc13);
      acc20 = fmaf(a4.z, b4.x, acc20); acc21 = fmaf(a4.z, b4.y, acc21);
      acc22 = fmaf(a4.z, b4.z, acc22); acc23 = fmaf(a4.z, b4.w, acc23);
      acc30 = fmaf(a4.w, b4.x, acc30); acc31 = fmaf(a4.w, b4.y, acc31);
      acc32 = fmaf(a4.w, b4.z, acc32); acc33 = fmaf(a4.w, b4.w, acc33);
    }
  }
  const int col = nt * 64 + tn * 4;
  float4 bias = *(const float4*)(ba + col);
  float4 o0 = {acc00 + bias.x, acc01 + bias.y, acc02 + bias.z, acc03 + bias.w};
  float4 o1 = {acc10 + bias.x, acc11 + bias.y, acc12 + bias.z, acc13 + bias.w};
  float4 o2 = {acc20 + bias.x, acc21 + bias.y, acc22 + bias.z, acc23 + bias.w};
  float4 o3 = {acc30 + bias.x, acc31 + bias.y, acc32 + bias.z, acc33 + bias.w};
  const size_t base = (size_t)(mt * 64 + tm * 4) * 512 + col;
  *(float4*)(ctx + base + 0 * 512) = o0;
  *(float4*)(ctx + base + 1 * 512) = o1;
  *(float4*)(ctx + base + 2 * 512) = o2;
  *(float4*)(ctx + base + 3 * 512) = o3;
}

// ---------------- persistent main loop: 256 blocks x 512 threads -------------
__launch_bounds__(512)
__global__ void pdecoder_main(PParams p) {
  __shared__ __align__(16) float smem[8704];   // 34.8 KB, aliased per phase
  float4* Xs = (float4*)smem;

  float* ws = p.ws;
  unsigned* bar = (unsigned*)ws;
  unsigned* gen = (unsigned*)ws + 32;   // separate cacheline
  unsigned tgt = 0;
  const int t = threadIdx.x, blk = blockIdx.x;
  const int nblk = gridDim.x;

  float* ctx    = ws + WS_CTX;
  float* hbuf   = ws + WS_H;
  float* cbuf   = ws + WS_C;
  float* hlbuf  = ws + WS_HL;
  float* inpbuf = ws + WS_INP;
  float* hsbuf  = ws + WS_HS;
  float* decbuf = ws + WS_DEC;
  float* attbuf = ws + WS_ATT;
  float* maskbuf= ws + WS_MASK;

  // ---- init state from inputs (ws is poisoned every call) ----
  {
    int idx = blk * 512 + t;                 // 131072 threads
    if (idx < Bn * Hn) { hbuf[idx] = p.h0[idx]; cbuf[idx] = p.c0[idx]; }
    if (idx < Bn * En) decbuf[idx] = p.dec0[idx];
    if (idx < Bn * Ln) maskbuf[idx] = 1.0f;
  }
  gsync(bar, gen, ++tgt, nblk);

  for (int step = 0; step < Ln; ++step) {
    // ================= Phase A: gates GEMM + LSTM elementwise ===============
    {
      const int bt = blk >> 6, ht = blk & 63;
      const int bi = t & 31, cg = t >> 5;        // cg 0..15 -> cols {cg, cg+16}
      const int j0 = cg & 7;
      const int g0 = cg >> 3, g1 = g0 + 2;
      const int gc0 = g0 * 512 + ht * 8 + j0;    // global gate-col in [0,2048)
      const int gc1 = g1 * 512 + ht * 8 + j0;
      float acc0 = 0.f, acc1 = 0.f;
#pragma unroll
      for (int kt = 0; kt < 4; ++kt) {
        __syncthreads();
        stage_tile(Xs, (kt < 2) ? decbuf : hbuf, bt, (kt & 1) * 256, t);
        __syncthreads();
        const float* W0 = ((kt < 2) ? p.Wih : p.Whh) + (size_t)gc0 * 512 + (kt & 1) * 256;
        const float* W1 = ((kt < 2) ? p.Wih : p.Whh) + (size_t)gc1 * 512 + (kt & 1) * 256;
        const float4* W04 = (const float4*)W0;
        const float4* W14 = (const float4*)W1;
#pragma unroll 4
        for (int k4 = 0; k4 < 64; ++k4) {
          float4 x = Xs[bi * 64 + (k4 ^ (bi & 7))];
          float4 w0 = W04[k4], w1 = W14[k4];
          acc0 = fmaf(x.x, w0.x, acc0); acc0 = fmaf(x.y, w0.y, acc0);
          acc0 = fmaf(x.z, w0.z, acc0); acc0 = fmaf(x.w, w0.w, acc0);
          acc1 = fmaf(x.x, w1.x, acc1); acc1 = fmaf(x.y, w1.y, acc1);
          acc1 = fmaf(x.z, w1.z, acc1); acc1 = fmaf(x.w, w1.w, acc1);
        }
      }
      __syncthreads();
      float* gs = smem;                       // [32][33]
      gs[bi * 33 + cg]      = acc0 + p.bih[gc0] + p.bhh[gc0];
      gs[bi * 33 + cg + 16] = acc1 + p.bih[gc1] + p.bhh[gc1];
      __syncthreads();
      if (t < 256) {
        const int j = t & 7, bi2 = t >> 3;
        float ig = gs[bi2 * 33 + j];
        float fg = gs[bi2 * 33 + 8 + j];
        float gg = gs[bi2 * 33 + 16 + j];
        float og = gs[bi2 * 33 + 24 + j];
        const int b = bt * 32 + bi2, h = ht * 8 + j;
        float cold = cbuf[b * 512 + h];
        float is = 1.f / (1.f + expf(-ig));
        float fs = 1.f / (1.f + expf(-fg));
        float os = 1.f / (1.f + expf(-og));
        float ct = fs * cold + is * tanhf(gg);
        float hl = os * tanhf(ct);
        cbuf[b * 512 + h] = ct;
        hlbuf[b * 512 + h] = hl;
      }
    }
    gsync(bar, gen, ++tgt, nblk);

    // ================= Phase B: inp = h_lstm @ Wa_in^T + ba_in ==============
    {
      const int bt = blk >> 6, ot = blk & 63;
      const int bi = t & 31, oj = t >> 5;     // valid for t<256: oj 0..7
      float acc = 0.f;
#pragma unroll
      for (int kt = 0; kt < 2; ++kt) {
        __syncthreads();
        stage_tile(Xs, hlbuf, bt, kt * 256, t);
        __syncthreads();
        if (t < 256) {
          const float4* Wr = (const float4*)(p.Wa_in + (size_t)(ot * 8 + oj) * 512 + kt * 256);
#pragma unroll 4
          for (int k4 = 0; k4 < 64; ++k4) {
            float4 x = Xs[bi * 64 + (k4 ^ (bi & 7))];
            float4 w = Wr[k4];
            acc = fmaf(x.x, w.x, acc); acc = fmaf(x.y, w.y, acc);
            acc = fmaf(x.z, w.z, acc); acc = fmaf(x.w, w.w, acc);
          }
        }
      }
      if (t < 256) {
        const int o = ot * 8 + oj;
        inpbuf[(bt * 32 + bi) * 512 + o] = acc + p.ba_in[o];
      }
    }
    gsync(bar, gen, ++tgt, nblk);

    // ================= Phase C: att[b,l] = sum_h V[h] tanh(inp+ctx), masked =
    {
      const int b = blk >> 1, ph = blk & 1;
      float* inp_s = smem;        // 512
      float* V_s   = smem + 512;  // 512
      inp_s[t] = inpbuf[b * 512 + t];
      V_s[t]   = p.V[t];
      __syncthreads();
      const int w = t >> 6, lane = t & 63;
      const float4* inp4 = (const float4*)inp_s;
      const float4* V4   = (const float4*)V_s;
      float4 i0 = inp4[lane],  i1 = inp4[64 + lane];
      float4 v0 = V4[lane],    v1 = V4[64 + lane];
      for (int i = 0; i < 16; ++i) {
        const int l = ph * 128 + w * 16 + i;
        const float4* row = (const float4*)(ctx + (size_t)(b * 256 + l) * 512);
        float4 c0 = row[lane], c1 = row[64 + lane];
        float a;
        a = v0.x * tanhf(i0.x + c0.x);
        a = fmaf(v0.y, tanhf(i0.y + c0.y), a);
        a = fmaf(v0.z, tanhf(i0.z + c0.z), a);
        a = fmaf(v0.w, tanhf(i0.w + c0.w), a);
        a = fmaf(v1.x, tanhf(i1.x + c1.x), a);
        a = fmaf(v1.y, tanhf(i1.y + c1.y), a);
        a = fmaf(v1.z, tanhf(i1.z + c1.z), a);
        a = fmaf(v1.w, tanhf(i1.w + c1.w), a);
#pragma unroll
        for (int off = 32; off > 0; off >>= 1) a += __shfl_xor(a, off, 64);
        if (lane == 0) {
          float m = maskbuf[b * 256 + l];
          attbuf[b * 256 + l] = (m == 0.f) ? -INFINITY : a;
        }
      }
    }
    gsync(bar, gen, ++tgt, nblk);

    // ===== Phase E: softmax + argmax + select/gather (ph==0) + hs pass ======
    {
      const int b = blk >> 1, ph = blk & 1;
      float* att_s   = smem;               // 256
      float* val_s   = smem + 256;         // 256
      int*   idx_s   = (int*)(smem + 512); // 256
      float* alpha_s = smem + 768;         // 256
      float* part_s  = smem + 1024;        // 256
      if (t < 256) {
        float a = attbuf[b * 256 + t];
        att_s[t] = a; val_s[t] = a; idx_s[t] = t;
      }
      __syncthreads();
      for (int s = 128; s > 0; s >>= 1) {
        if (t < s) {
          float v1 = val_s[t], v2 = val_s[t + s];
          int   i1 = idx_s[t], i2 = idx_s[t + s];
          if (v2 > v1 || (v2 == v1 && i2 < i1)) { val_s[t] = v2; idx_s[t] = i2; }
        }
        __syncthreads();
      }
      const float m = val_s[0];
      const int am = idx_s[0];
      __syncthreads();
      if (t < 256) {
        float e = expf(att_s[t] - m);   // exp(-inf)=0 for masked
        alpha_s[t] = e; val_s[t] = e;
      }
      __syncthreads();
      for (int s = 128; s > 0; s >>= 1) {
        if (t < s) val_s[t] += val_s[t + s];
        __syncthreads();
      }
      const float Z = val_s[0];
      __syncthreads();
      if (t < 256) alpha_s[t] = alpha_s[t] / Z;
      __syncthreads();
      if (ph == 0) {
        if (t < 256) p.out[(size_t)b * Ln * Ln + (size_t)step * Ln + t] = alpha_s[t];
        if (t == 0) {
          p.out[OUT_PTR + (size_t)b * Ln + step] = (float)am;
          maskbuf[b * 256 + am] = 0.f;
        }
        decbuf[b * 512 + t] = p.emb[(size_t)(b * 256 + am) * 512 + t];
      }
      // hs[b, ph*256 + hi] = sum_l alpha[l] * ctx[b,l,h]
      const int hi = t & 255, lp = t >> 8;
      const int h = ph * 256 + hi;
      float acc = 0.f;
      const float* cb = ctx + (size_t)b * 256 * 512 + h;
#pragma unroll 4
      for (int l = lp * 128; l < lp * 128 + 128; ++l)
        acc = fmaf(alpha_s[l], cb[(size_t)l * 512], acc);
      if (lp == 1) part_s[hi] = acc;
      __syncthreads();
      if (lp == 0) hsbuf[b * 512 + h] = acc + part_s[hi];
    }
    gsync(bar, gen, ++tgt, nblk);

    // ========== Phase F: h = tanh([hs, h_lstm] @ Who^T + bho) ===============
    {
      const int bt = blk >> 6, ot = blk & 63;
      const int bi = t & 31, s = t >> 5;       // s 0..15
      const int oj = s & 7, kh = s >> 3;
      const int o = ot * 8 + oj;
      float acc = 0.f;
#pragma unroll
      for (int kt = 0; kt < 4; ++kt) {
        __syncthreads();
        stage_tile(Xs, (kt < 2) ? hsbuf : hlbuf, bt, (kt & 1) * 256, t);
        __syncthreads();
        if ((kt >> 1) == kh) {
          const float4* Wr = (const float4*)(p.Who + (size_t)o * 1024 + kt * 256);
#pragma unroll 4
          for (int k4 = 0; k4 < 64; ++k4) {
            float4 x = Xs[bi * 64 + (k4 ^ (bi & 7))];
            float4 w = Wr[k4];
            acc = fmaf(x.x, w.x, acc); acc = fmaf(x.y, w.y, acc);
            acc = fmaf(x.z, w.z, acc); acc = fmaf(x.w, w.w, acc);
          }
        }
      }
      __syncthreads();
      float* part = smem;                       // [32][17]
      part[bi * 17 + s] = acc;
      __syncthreads();
      if (t < 256) {
        const int bi2 = t & 31, oj2 = t >> 5;   // 0..7
        float v = part[bi2 * 17 + oj2] + part[bi2 * 17 + 8 + oj2];
        const int o2 = ot * 8 + oj2, b = bt * 32 + bi2;
        hbuf[b * 512 + o2] = tanhf(v + p.bho[o2]);
      }
    }
    gsync(bar, gen, ++tgt, nblk);
  }

  // ---- epilogue: hF, cF ----
  {
    int idx = blk * 512 + t;
    if (idx < Bn * Hn) {
      p.out[OUT_HF + idx] = hbuf[idx];
      p.out[OUT_CF + idx] = cbuf[idx];
    }
  }
}

extern "C" void kernel_launch(void* const* d_in, const int* in_sizes, int n_in,
                              void* d_out, int out_size, void* d_ws, size_t ws_size,
                              hipStream_t stream) {
  (void)in_sizes; (void)n_in; (void)out_size; (void)ws_size;
  const float* emb     = (const float*)d_in[0];
  const float* dec0    = (const float*)d_in[1];
  const float* h0      = (const float*)d_in[2];
  const float* c0      = (const float*)d_in[3];
  const float* context = (const float*)d_in[4];
  const float* Wih     = (const float*)d_in[5];
  const float* bih     = (const float*)d_in[6];
  const float* Whh     = (const float*)d_in[7];
  const float* bhh     = (const float*)d_in[8];
  const float* Who     = (const float*)d_in[9];
  const float* bho     = (const float*)d_in[10];
  const float* Wa_in   = (const float*)d_in[11];
  const float* ba_in   = (const float*)d_in[12];
  const float* Wa_ctx  = (const float*)d_in[13];
  const float* ba_ctx  = (const float*)d_in[14];
  const float* V       = (const float*)d_in[15];
  float* ws  = (float*)d_ws;
  float* out = (float*)d_out;

  // zero the barrier words (ws is re-poisoned 0xAA before every timed launch)
  hipMemsetAsync(d_ws, 0, 4096, stream);

  hipLaunchKernelGGL(ctx_precompute, dim3(4096), dim3(256), 0, stream,
                     context, Wa_ctx, ba_ctx, ws);

  PParams prm{emb, dec0, h0, c0, Wih, bih, Whh, bhh, Who, bho, Wa_in, ba_in, V, ws, out};
  void* args[] = {&prm};
  hipLaunchCooperativeKernel((const void*)pdecoder_main, dim3(256), dim3(512),
                             args, 0, stream);
}

// Round 4
// 43178.983 us; speedup vs baseline: 1.4085x; 1.4085x over previous
//
#include <hip/hip_runtime.h>
#include <math.h>

namespace {
constexpr int Bn = 128, Ln = 256, En = 512, Hn = 512;

// ws layout (float offsets)
constexpr long WS_CTX  = 1024;                       // [B][L][H] = ctx[b,l,o]
constexpr long WS_H    = WS_CTX + (long)Bn * Ln * Hn;
constexpr long WS_C    = WS_H   + (long)Bn * Hn;
constexpr long WS_HL   = WS_C   + (long)Bn * Hn;
constexpr long WS_INP  = WS_HL  + (long)Bn * Hn;
constexpr long WS_HS   = WS_INP + (long)Bn * Hn;
constexpr long WS_DEC  = WS_HS  + (long)Bn * Hn;
constexpr long WS_ATT  = WS_DEC + (long)Bn * En;
constexpr long WS_MASK = WS_ATT + (long)Bn * Ln;

// out layout (float offsets)
constexpr long OUT_PTR = (long)Bn * Ln * Ln;   // 8388608
constexpr long OUT_HF  = OUT_PTR + (long)Bn * Ln;
constexpr long OUT_CF  = OUT_HF + (long)Bn * Hn;
}

struct PParams {
  const float *emb, *dec0, *h0, *c0;
  const float *Wih, *bih, *Whh, *bhh;
  const float *Who, *bho, *Wa_in, *ba_in, *V;
  float *ws, *out;
};

// ------- sharded grid barrier (256 blocks = 4 shards x 64, 1 block/CU) ------
// Spin is RELAXED (agent-scope relaxed atomic loads are device-coherent, so
// they observe the remote release without emitting buffer_inv per poll). ONE
// acquire load after spin-exit invalidates stale L1/L2 once. Arrival RMW is
// ACQ_REL: release part writes back this block's dirty lines before arrival.
__device__ __forceinline__ void gsync(unsigned* ub, unsigned target, int blk) {
  __syncthreads();
  if (threadIdx.x == 0) {
    unsigned* shard  = ub + (blk & 3) * 64;   // 256B apart
    unsigned* master = ub + 512;
    unsigned* gen    = ub + 576;
    bool released = false;
    unsigned n = __hip_atomic_fetch_add(shard, 1u, __ATOMIC_ACQ_REL, __HIP_MEMORY_SCOPE_AGENT);
    if (n == 63u) {
      __hip_atomic_store(shard, 0u, __ATOMIC_RELAXED, __HIP_MEMORY_SCOPE_AGENT);
      unsigned mn = __hip_atomic_fetch_add(master, 1u, __ATOMIC_ACQ_REL, __HIP_MEMORY_SCOPE_AGENT);
      if (mn == 3u) {
        __hip_atomic_store(master, 0u, __ATOMIC_RELAXED, __HIP_MEMORY_SCOPE_AGENT);
        __hip_atomic_store(gen, target, __ATOMIC_RELEASE, __HIP_MEMORY_SCOPE_AGENT);
        released = true;
      }
    }
    if (!released) {
      while (__hip_atomic_load(gen, __ATOMIC_RELAXED, __HIP_MEMORY_SCOPE_AGENT) < target)
        __builtin_amdgcn_s_sleep(2);
      (void)__hip_atomic_load(gen, __ATOMIC_ACQUIRE, __HIP_MEMORY_SCOPE_AGENT);
    }
  }
  __syncthreads();
}

// stage one [32 rows x 256 k] fp32 tile into LDS as swizzled float4 (Xs[32][64])
// 1024-thread variant: 32 threads per row, 2 float4 each.
__device__ __forceinline__ void stage_tile(float4* __restrict__ Xs, const float* __restrict__ src,
                                           int bt, int koff, int tid) {
  const int r  = tid >> 5;    // 0..31
  const int ks = tid & 31;
  const float4* g = (const float4*)(src + (size_t)(bt * 32 + r) * 512 + koff);
#pragma unroll
  for (int u = 0; u < 2; ++u) {
    int k4 = ks * 2 + u;
    Xs[r * 64 + (k4 ^ (r & 7))] = g[k4];   // XOR swizzle breaks b128 bank aliasing
  }
}

// ---------------- ctx precompute: ctx[b,l,o] = context[b,l,:]·Wa_ctx[o,:] + ba_ctx[o]
__launch_bounds__(256)
__global__ void ctx_precompute(const float* __restrict__ context,
                               const float* __restrict__ Wa,
                               const float* __restrict__ ba,
                               float* __restrict__ ws) {
  __shared__ __align__(16) float As[16 * 68];
  __shared__ __align__(16) float Wsm[16 * 68];
  float* ctx = ws + WS_CTX;
  const int mt = blockIdx.x >> 3;
  const int nt = blockIdx.x & 7;
  const int t = threadIdx.x;
  const int tm = t & 15, tn = t >> 4;
  float acc00=0,acc01=0,acc02=0,acc03=0, acc10=0,acc11=0,acc12=0,acc13=0;
  float acc20=0,acc21=0,acc22=0,acc23=0, acc30=0,acc31=0,acc32=0,acc33=0;

  for (int kt = 0; kt < 32; ++kt) {
    __syncthreads();
    {
      const int m = t >> 2, k4 = t & 3;
      float4 a = *(const float4*)(context + (size_t)(mt * 64 + m) * 512 + kt * 16 + k4 * 4);
      As[(k4*4+0)*68 + m] = a.x; As[(k4*4+1)*68 + m] = a.y;
      As[(k4*4+2)*68 + m] = a.z; As[(k4*4+3)*68 + m] = a.w;
      float4 w = *(const float4*)(Wa + (size_t)(nt * 64 + m) * 512 + kt * 16 + k4 * 4);
      Wsm[(k4*4+0)*68 + m] = w.x; Wsm[(k4*4+1)*68 + m] = w.y;
      Wsm[(k4*4+2)*68 + m] = w.z; Wsm[(k4*4+3)*68 + m] = w.w;
    }
    __syncthreads();
#pragma unroll
    for (int k = 0; k < 16; ++k) {
      float4 a4 = *(const float4*)(As + k * 68 + tm * 4);
      float4 b4 = *(const float4*)(Wsm + k * 68 + tn * 4);
      acc00 = fmaf(a4.x, b4.x, acc00); acc01 = fmaf(a4.x, b4.y, acc01);
      acc02 = fmaf(a4.x, b4.z, acc02); acc03 = fmaf(a4.x, b4.w, acc03);
      acc10 = fmaf(a4.y, b4.x, acc10); acc11 = fmaf(a4.y, b4.y, acc11);
      acc12 = fmaf(a4.y, b4.z, acc12); acc13 = fmaf(a4.y, b4.w, acc13);
      acc20 = fmaf(a4.z, b4.x, acc20); acc21 = fmaf(a4.z, b4.y, acc21);
      acc22 = fmaf(a4.z, b4.z, acc22); acc23 = fmaf(a4.z, b4.w, acc23);
      acc30 = fmaf(a4.w, b4.x, acc30); acc31 = fmaf(a4.w, b4.y, acc31);
      acc32 = fmaf(a4.w, b4.z, acc32); acc33 = fmaf(a4.w, b4.w, acc33);
    }
  }
  const int col = nt * 64 + tn * 4;
  float4 bias = *(const float4*)(ba + col);
  float4 o0 = {acc00 + bias.x, acc01 + bias.y, acc02 + bias.z, acc03 + bias.w};
  float4 o1 = {acc10 + bias.x, acc11 + bias.y, acc12 + bias.z, acc13 + bias.w};
  float4 o2 = {acc20 + bias.x, acc21 + bias.y, acc22 + bias.z, acc23 + bias.w};
  float4 o3 = {acc30 + bias.x, acc31 + bias.y, acc32 + bias.z, acc33 + bias.w};
  const size_t base = (size_t)(mt * 64 + tm * 4) * 512 + col;
  *(float4*)(ctx + base + 0 * 512) = o0;
  *(float4*)(ctx + base + 1 * 512) = o1;
  *(float4*)(ctx + base + 2 * 512) = o2;
  *(float4*)(ctx + base + 3 * 512) = o3;
}

// --------- persistent main loop: 256 blocks x 1024 threads (1/CU, 16 waves) --
// All trajectory-relevant arithmetic is a bit-exact clone of the R1 kernel
// (which passed with exact pointers): per-output fma order, tree softmax with
// expf, tree argmax tie rules, Phase F pairwise K-split. Only barrier, wave
// count, and provably bit-neutral mask-skips differ.
__launch_bounds__(1024, 4)
__global__ void pdecoder_main(PParams p) {
  __shared__ __align__(16) float smem[8192];   // 32 KB
  float4* Xs = (float4*)smem;

  float* ws = p.ws;
  unsigned* ub = (unsigned*)ws;
  unsigned tgt = 0;
  const int t = threadIdx.x, blk = blockIdx.x;

  float* ctx    = ws + WS_CTX;
  float* hbuf   = ws + WS_H;
  float* cbuf   = ws + WS_C;
  float* hlbuf  = ws + WS_HL;
  float* inpbuf = ws + WS_INP;
  float* hsbuf  = ws + WS_HS;
  float* decbuf = ws + WS_DEC;
  float* attbuf = ws + WS_ATT;
  float* maskbuf= ws + WS_MASK;

  // ---- init state (ws poisoned every call) ----
  {
    int idx = blk * 1024 + t;
    if (idx < Bn * Hn) { hbuf[idx] = p.h0[idx]; cbuf[idx] = p.c0[idx]; }
    if (idx < Bn * En) decbuf[idx] = p.dec0[idx];
    if (idx < Bn * Ln) maskbuf[idx] = 1.0f;
  }
  gsync(ub, ++tgt, blk);

  for (int step = 0; step < Ln; ++step) {
    // ===== Phase A: gates = dec@Wih^T + h@Whh^T + b; LSTM elementwise =======
    // One gate-output per thread; K fully sequential (kt 0..3, k4 0..63,
    // xyzw) — exact R1 per-output order.
    {
      const int bt = blk >> 6, ht = blk & 63;       // 4 b-tiles x 64 h-groups(8)
      const int bi = t & 31, cg = t >> 5;           // cg 0..31 = g*8 + j0
      const int j0 = cg & 7, g = cg >> 3;
      const int gc = g * 512 + ht * 8 + j0;
      float acc = 0.f;
#pragma unroll
      for (int kt = 0; kt < 4; ++kt) {
        __syncthreads();
        stage_tile(Xs, (kt < 2) ? decbuf : hbuf, bt, (kt & 1) * 256, t);
        __syncthreads();
        const float4* W4 = (const float4*)(((kt < 2) ? p.Wih : p.Whh) + (size_t)gc * 512 + (kt & 1) * 256);
#pragma unroll 4
        for (int k4 = 0; k4 < 64; ++k4) {
          float4 x = Xs[bi * 64 + (k4 ^ (bi & 7))];
          float4 w = W4[k4];
          acc = fmaf(x.x, w.x, acc); acc = fmaf(x.y, w.y, acc);
          acc = fmaf(x.z, w.z, acc); acc = fmaf(x.w, w.w, acc);
        }
      }
      __syncthreads();
      float* gs = smem;                       // [32][33] = 1056
      gs[bi * 33 + cg] = acc + p.bih[gc] + p.bhh[gc];
      __syncthreads();
      if (t < 256) {
        const int j = t & 7, bi2 = t >> 3;
        float ig = gs[bi2 * 33 + j];
        float fg = gs[bi2 * 33 + 8 + j];
        float gg = gs[bi2 * 33 + 16 + j];
        float og = gs[bi2 * 33 + 24 + j];
        const int b = bt * 32 + bi2, h = ht * 8 + j;
        float cold = cbuf[b * 512 + h];
        float is = 1.f / (1.f + expf(-ig));
        float fs = 1.f / (1.f + expf(-fg));
        float os = 1.f / (1.f + expf(-og));
        float ct = fs * cold + is * tanhf(gg);
        float hl = os * tanhf(ct);
        cbuf[b * 512 + h] = ct;
        hlbuf[b * 512 + h] = hl;
      }
    }
    gsync(ub, ++tgt, blk);

    // ===== Phase B: inp = h_lstm @ Wa_in^T + ba_in (full-K sequential) ======
    {
      const int bt = blk >> 6, ot = blk & 63;
      const int bi = t & 31, oj = t >> 5;     // valid for t<256
      float acc = 0.f;
#pragma unroll
      for (int kt = 0; kt < 2; ++kt) {
        __syncthreads();
        stage_tile(Xs, hlbuf, bt, kt * 256, t);
        __syncthreads();
        if (t < 256) {
          const float4* Wr = (const float4*)(p.Wa_in + (size_t)(ot * 8 + oj) * 512 + kt * 256);
#pragma unroll 4
          for (int k4 = 0; k4 < 64; ++k4) {
            float4 x = Xs[bi * 64 + (k4 ^ (bi & 7))];
            float4 w = Wr[k4];
            acc = fmaf(x.x, w.x, acc); acc = fmaf(x.y, w.y, acc);
            acc = fmaf(x.z, w.z, acc); acc = fmaf(x.w, w.w, acc);
          }
        }
      }
      if (t < 256) {
        const int o = ot * 8 + oj;
        inpbuf[(bt * 32 + bi) * 512 + o] = acc + p.ba_in[o];
      }
    }
    gsync(ub, ++tgt, blk);

    // ===== Phase C: att[b,l] = sum_h V[h] tanh(inp+ctx), mask-skipped =======
    // Skipped (masked) rows get att=-inf without compute; unmasked rows' att
    // bits are unaffected by the skip (row-independent) — R1-identical attbuf.
    {
      const int b = blk >> 1, ph = blk & 1;   // 128 l-rows per block, 16 waves
      float* inp_s = smem;          // 512
      float* V_s   = smem + 512;    // 512
      if (t < 512) { inp_s[t] = inpbuf[b * 512 + t]; V_s[t] = p.V[t]; }
      __syncthreads();
      const int w = t >> 6, lane = t & 63;
      const float4* inp4 = (const float4*)inp_s;
      const float4* V4   = (const float4*)V_s;
      float4 i0 = inp4[lane],  i1 = inp4[64 + lane];
      float4 v0 = V4[lane],    v1 = V4[64 + lane];
      for (int i = 0; i < 8; ++i) {
        const int l = ph * 128 + w * 8 + i;
        float msk = maskbuf[b * 256 + l];      // wave-uniform
        if (msk == 0.f) {
          if (lane == 0) attbuf[b * 256 + l] = -INFINITY;
          continue;
        }
        const float4* row = (const float4*)(ctx + (size_t)(b * 256 + l) * 512);
        float4 c0 = row[lane], c1 = row[64 + lane];
        float a;
        a = v0.x * tanhf(i0.x + c0.x);
        a = fmaf(v0.y, tanhf(i0.y + c0.y), a);
        a = fmaf(v0.z, tanhf(i0.z + c0.z), a);
        a = fmaf(v0.w, tanhf(i0.w + c0.w), a);
        a = fmaf(v1.x, tanhf(i1.x + c1.x), a);
        a = fmaf(v1.y, tanhf(i1.y + c1.y), a);
        a = fmaf(v1.z, tanhf(i1.z + c1.z), a);
        a = fmaf(v1.w, tanhf(i1.w + c1.w), a);
#pragma unroll
        for (int off = 32; off > 0; off >>= 1) a += __shfl_xor(a, off, 64);
        if (lane == 0) attbuf[b * 256 + l] = a;
      }
    }
    gsync(ub, ++tgt, blk);

    // ===== Phase E: tree softmax + argmax + outputs + hs (R1 bit-exact) =====
    {
      const int b = blk >> 1, ph = blk & 1;
      float* att_s   = smem;               // 256
      float* val_s   = smem + 256;         // 256
      int*   idx_s   = (int*)(smem + 512); // 256
      float* alpha_s = smem + 768;         // 256
      float* part_s  = smem + 1024;        // 256
      if (t < 256) {
        float a = attbuf[b * 256 + t];
        att_s[t] = a; val_s[t] = a; idx_s[t] = t;
      }
      __syncthreads();
      for (int s = 128; s > 0; s >>= 1) {
        if (t < s) {
          float v1 = val_s[t], v2 = val_s[t + s];
          int   i1 = idx_s[t], i2 = idx_s[t + s];
          if (v2 > v1 || (v2 == v1 && i2 < i1)) { val_s[t] = v2; idx_s[t] = i2; }
        }
        __syncthreads();
      }
      const float m = val_s[0];
      const int am = idx_s[0];
      __syncthreads();
      if (t < 256) {
        float e = expf(att_s[t] - m);   // exp(-inf)=0 for masked
        alpha_s[t] = e; val_s[t] = e;
      }
      __syncthreads();
      for (int s = 128; s > 0; s >>= 1) {
        if (t < s) val_s[t] += val_s[t + s];
        __syncthreads();
      }
      const float Z = val_s[0];
      __syncthreads();
      if (t < 256) alpha_s[t] = alpha_s[t] / Z;
      __syncthreads();
      if (ph == 0) {
        if (t < 256) p.out[(size_t)b * Ln * Ln + (size_t)step * Ln + t] = alpha_s[t];
        if (t == 0) {
          p.out[OUT_PTR + (size_t)b * Ln + step] = (float)am;
          maskbuf[b * 256 + am] = 0.f;
        }
        if (t < 512) decbuf[b * 512 + t] = p.emb[((size_t)(b * 256) + am) * 512 + t];
      }
      // hs[b, ph*256 + hi] = sum_l alpha[l] * ctx[b,l,h] — R1 order (2 l-halves
      // of 128 sequential each, pairwise combined). alpha==0 skip is bitwise
      // neutral: fmaf(0,c,acc)==acc (acc starts +0, never -0).
      const int hi = t & 255, lp = (t >> 8) & 1;
      const int h = ph * 256 + hi;
      float acc = 0.f;
      if (t < 512) {
        const float* cb = ctx + (size_t)b * 256 * 512 + h;
#pragma unroll 4
        for (int l = lp * 128; l < lp * 128 + 128; ++l) {
          float al = alpha_s[l];
          if (al != 0.f) acc = fmaf(al, cb[(size_t)l * 512], acc);
        }
      }
      if (t < 512 && lp == 1) part_s[hi] = acc;
      __syncthreads();
      if (t < 512 && lp == 0) hsbuf[(size_t)b * 512 + h] = acc + part_s[hi];
    }
    gsync(ub, ++tgt, blk);

    // ===== Phase F: h = tanh([hs, hl] @ Who^T + bho) — R1 K-split (2-way) ===
    {
      const int bt = blk >> 6, ot = blk & 63;
      const int bi = t & 31, s = (t >> 5) & 15;  // active t<512: s = kh*8 + oj
      const int oj = s & 7, kh = s >> 3;
      const int o = ot * 8 + oj;
      float acc = 0.f;
#pragma unroll
      for (int kt = 0; kt < 4; ++kt) {
        __syncthreads();
        stage_tile(Xs, (kt < 2) ? hsbuf : hlbuf, bt, (kt & 1) * 256, t);
        __syncthreads();
        if (t < 512 && (kt >> 1) == kh) {
          const float4* Wr = (const float4*)(p.Who + (size_t)o * 1024 + kt * 256);
#pragma unroll 4
          for (int k4 = 0; k4 < 64; ++k4) {
            float4 x = Xs[bi * 64 + (k4 ^ (bi & 7))];
            float4 w = Wr[k4];
            acc = fmaf(x.x, w.x, acc); acc = fmaf(x.y, w.y, acc);
            acc = fmaf(x.z, w.z, acc); acc = fmaf(x.w, w.w, acc);
          }
        }
      }
      __syncthreads();
      float* part = smem;                       // [32][17]
      if (t < 512) part[bi * 17 + s] = acc;
      __syncthreads();
      if (t < 256) {
        const int bi2 = t & 31, oj2 = t >> 5;   // 0..7
        float v = part[bi2 * 17 + oj2] + part[bi2 * 17 + 8 + oj2];
        const int o2 = ot * 8 + oj2, bb = bt * 32 + bi2;
        hbuf[bb * 512 + o2] = tanhf(v + p.bho[o2]);
      }
    }
    gsync(ub, ++tgt, blk);
  }

  // ---- epilogue: hF, cF ----
  {
    int idx = blk * 1024 + t;
    if (idx < Bn * Hn) {
      p.out[OUT_HF + idx] = hbuf[idx];
      p.out[OUT_CF + idx] = cbuf[idx];
    }
  }
}

extern "C" void kernel_launch(void* const* d_in, const int* in_sizes, int n_in,
                              void* d_out, int out_size, void* d_ws, size_t ws_size,
                              hipStream_t stream) {
  (void)in_sizes; (void)n_in; (void)out_size; (void)ws_size;
  const float* emb     = (const float*)d_in[0];
  const float* dec0    = (const float*)d_in[1];
  const float* h0      = (const float*)d_in[2];
  const float* c0      = (const float*)d_in[3];
  const float* context = (const float*)d_in[4];
  const float* Wih     = (const float*)d_in[5];
  const float* bih     = (const float*)d_in[6];
  const float* Whh     = (const float*)d_in[7];
  const float* bhh     = (const float*)d_in[8];
  const float* Who     = (const float*)d_in[9];
  const float* bho     = (const float*)d_in[10];
  const float* Wa_in   = (const float*)d_in[11];
  const float* ba_in   = (const float*)d_in[12];
  const float* Wa_ctx  = (const float*)d_in[13];
  const float* ba_ctx  = (const float*)d_in[14];
  const float* V       = (const float*)d_in[15];
  float* ws  = (float*)d_ws;
  float* out = (float*)d_out;

  hipMemsetAsync(d_ws, 0, 4096, stream);   // barrier words

  hipLaunchKernelGGL(ctx_precompute, dim3(4096), dim3(256), 0, stream,
                     context, Wa_ctx, ba_ctx, ws);

  PParams prm{emb, dec0, h0, c0, Wih, bih, Whh, bhh, Who, bho, Wa_in, ba_in, V, ws, out};
  void* args[] = {&prm};
  hipLaunchCooperativeKernel((const void*)pdecoder_main, dim3(256), dim3(1024),
                             args, 0, stream);
}